// Round 4
// baseline (678.138 us; speedup 1.0000x reference)
//
#include <hip/hip_runtime.h>
#include <hip/hip_bf16.h>

// Problem constants
#define Mdim 2048
#define Ndim 8192
#define Kdim 8192
#define NT 128           // K-tiles of BK=64
#define BM 256
#define BN 128

typedef __bf16 bf16x8 __attribute__((ext_vector_type(8)));
typedef float f32x4 __attribute__((ext_vector_type(4)));
typedef unsigned short ushort4v __attribute__((ext_vector_type(4)));

__device__ __forceinline__ unsigned short f2bf_rne(float f) {
    unsigned u = __float_as_uint(f);
    u += 0x7fffu + ((u >> 16) & 1u);
    return (unsigned short)(u >> 16);
}

// ---------------------------------------------------------------------------
// k_prep: x fp32 -> bf16 only.
// ---------------------------------------------------------------------------
__global__ __launch_bounds__(256) void k_prep(const float* __restrict__ x,
                                              unsigned short* __restrict__ xb) {
    const size_t u = (size_t)blockIdx.x * 256 + threadIdx.x;  // 0..4194303
    float4 a = ((const float4*)x)[u];
    ushort4v o;
    o[0] = f2bf_rne(a.x); o[1] = f2bf_rne(a.y);
    o[2] = f2bf_rne(a.z); o[3] = f2bf_rne(a.w);
    ((ushort4v*)xb)[u] = o;
}

// ---------------------------------------------------------------------------
// Fused dequant+GEMM, producer/consumer wave specialization.
//   C[M,N] = A[M,K] * W[N,K]^T;  A bf16 staged via global_load_lds,
//   W decoded from 3-bit packed + codebook by PRODUCER waves into LDS.
// Waves 0-3: consumers (pure ds_read + MFMA). Waves 4-7: producers
// (decode VALU + A-DMA). Round-robin wave->SIMD placement gives each SIMD
// one of each; MFMA and VALU pipes overlap (m114). One barrier per K-tile.
// Double-buffered LA/LB by tile parity; producer fills buf^1 for T+1 while
// consumers eat buf for T. Producer-private vmcnt: end-of-tile vmcnt(4)
// forces its 8 gld16 (A for T+1) and leaves the 4 packed/cb loads (for
// T+2's decode) in flight across the barrier. Decode bit-logic identical
// to the R3 kernel (correctness-proven, absmax unchanged).
// LDS: LA 2x32KB + LB 2x16KB = 96KB. Same XOR-chunk swizzle both sides
// (slot s of row r holds global k-chunk s ^ (r&7)); conflict-free reads.
// ---------------------------------------------------------------------------
__device__ __forceinline__ void gld16(const unsigned short* g, unsigned short* l) {
    __builtin_amdgcn_global_load_lds(
        (const __attribute__((address_space(1))) unsigned int*)g,
        (__attribute__((address_space(3))) unsigned int*)l, 16, 0, 0);
}

#define BAR()    asm volatile("s_barrier" ::: "memory")
#define FENCE()  asm volatile("" ::: "memory")
#define LGKM0()  asm volatile("s_waitcnt lgkmcnt(0)" ::: "memory")
#define VMCNT(n) asm volatile("s_waitcnt vmcnt(" #n ")" ::: "memory")

// Decode one 8-elem group (24 payload bits) vs bf16-packed codebook pairs.
__device__ __forceinline__ uint4 dec_group(unsigned b, unsigned P0, unsigned P1,
                                           unsigned P2, unsigned P3) {
    uint4 o;
#pragma unroll
    for (int k = 0; k < 4; ++k) {
        unsigned ia = (b >> (6 * k)) & 3u;
        unsigned ib = (b >> (6 * k + 3)) & 3u;
        unsigned sel = ia * 0x0202u + 0x01000100u + ((ib * 0x0202u) << 16);
        unsigned lo = __builtin_amdgcn_perm(P1, P0, sel);
        unsigned hi = __builtin_amdgcn_perm(P3, P2, sel);
        unsigned mA = (unsigned)((int)(b << (29 - 6 * k)) >> 31);
        unsigned mB = (unsigned)((int)(b << (26 - 6 * k)) >> 31);
        unsigned m = (mA & 0xFFFFu) | (mB & 0xFFFF0000u);
        (&o.x)[k] = (hi & m) | (lo & ~m);
    }
    return o;
}

__global__ __launch_bounds__(512, 2) void k_gemm(const unsigned short* __restrict__ A,
                                                 const int* __restrict__ packed,
                                                 const float* __restrict__ cb,
                                                 float* __restrict__ C) {
    __shared__ unsigned short LA[2 * 16384];   // [buf][256][64] = 64 KB
    __shared__ unsigned short LB[2 * 8192];    // [buf][128][64] = 32 KB

    const int tid  = threadIdx.x;
    const int lane = tid & 63;
    const int wave = tid >> 6;               // 0..7

    const int bid = blockIdx.x;              // 512 blocks
    const int bm = (bid & 7) * BM;           // XCD i owns A panel i (4MB, L2)
    const int bn = (bid >> 3) * BN;          // 0..63

    // ---------------- producer addressing (waves 4-7) ----------------
    const int plane = (tid - 256) & 255;     // 0..255 for producers
    const int arow0 = plane >> 3;            // 0..31
    const int acol  = ((plane & 7) ^ (arow0 & 7)) * 8;
    const unsigned short* Aga = A + (size_t)(bm + arow0) * Kdim + acol;

    const int brow = plane >> 1;             // 0..127
    const int dp   = plane & 1;
    const int dp4  = dp * 4;
    const int brlo = brow & 7;
    const int* Pg   = packed + (size_t)(bn + brow) * 3072 + dp * 12;
    const float* Cg = cb + (size_t)(bn + brow) * 512;

    // ---------------- consumer addressing (waves 0-3) ----------------
    const int r15 = lane & 15;
    const int q   = lane >> 4;
    const int rlo = r15 & 7;
    const int qm  = wave >> 1;               // 0..1 (consumer waves only)
    const int qn  = wave & 1;                // 0..1
    const int aro = qm * 128 + r15;
    const int bro = qn * 64 + r15;
    const int ch0 = ((0 + q) ^ rlo) * 8;
    const int ch1 = ((4 + q) ^ rlo) * 8;

    f32x4 acc[8][4];
    const f32x4 zero = {0.f, 0.f, 0.f, 0.f};
#pragma unroll
    for (int i = 0; i < 8; ++i)
#pragma unroll
        for (int j = 0; j < 4; ++j) acc[i][j] = zero;

    // producer double reg sets for packed payload + codebook
    int4 pA0, pA1, pA2, pB0, pB1, pB2;
    float4 cA0, cA1, cB0, cB1;

#define GLD_A(T1, BUFP) do {                                                      \
    unsigned short* _ld = LA + (BUFP) * 16384 + plane * 8;                        \
    const unsigned short* _sg = Aga + (size_t)(T1) * 64;                          \
    _Pragma("unroll") for (int r = 0; r < 8; ++r)                                 \
        gld16(_sg + (size_t)(r * 32) * Kdim, _ld + r * 2048);                     \
    FENCE();                                                                      \
} while (0)

#define DECG(G, W0, W1, W2) do {                                                  \
    unsigned _b = (unsigned)(W0) | ((unsigned)(W1) << 8) | ((unsigned)(W2) << 16);\
    uint4 _o = dec_group(_b, cP0, cP1, cP2, cP3);                                 \
    *(uint4*)&_wb[((dp4 + (G)) ^ brlo) << 3] = _o;                                \
} while (0)

#define DECODE_TILE(BUFP, dq0, dq1, dq2, dc0, dc1) do {                           \
    unsigned cP0 = (unsigned)f2bf_rne(dc0.x) | ((unsigned)f2bf_rne(dc0.y) << 16); \
    unsigned cP1 = (unsigned)f2bf_rne(dc0.z) | ((unsigned)f2bf_rne(dc0.w) << 16); \
    unsigned cP2 = (unsigned)f2bf_rne(dc1.x) | ((unsigned)f2bf_rne(dc1.y) << 16); \
    unsigned cP3 = (unsigned)f2bf_rne(dc1.z) | ((unsigned)f2bf_rne(dc1.w) << 16); \
    unsigned short* _wb = LB + (BUFP) * 8192 + brow * 64;                         \
    DECG(0, dq0.x, dq0.y, dq0.z);                                                 \
    DECG(1, dq0.w, dq1.x, dq1.y);                                                 \
    DECG(2, dq1.z, dq1.w, dq2.x);                                                 \
    DECG(3, dq2.y, dq2.z, dq2.w);                                                 \
} while (0)

// Producer tile body: stage A(T+1) via DMA, decode B(T+1) from regs loaded
// last tile, issue packed/cb loads for T+2. End: force the 8 gld16 (A T+1
// must land before the barrier), leave the 4 reg-loads in flight.
#define PRODUCE(T, dq0,dq1,dq2, dc0,dc1, lq0,lq1,lq2, lc0,lc1) do {               \
    if ((T) + 1 < NT) {                                                           \
        GLD_A((T) + 1, ((T) + 1) & 1);                                            \
        DECODE_TILE(((T) + 1) & 1, dq0, dq1, dq2, dc0, dc1);                      \
    }                                                                             \
    if ((T) + 2 < NT) {                                                           \
        const int4* _pp = (const int4*)(Pg + (size_t)((T) + 2) * 24);             \
        lq0 = _pp[0]; lq1 = _pp[1]; lq2 = _pp[2];                                 \
        const float4* _cc = (const float4*)(Cg + (size_t)(((T) + 2) >> 1) * 8);   \
        lc0 = _cc[0]; lc1 = _cc[1];                                               \
    }                                                                             \
    LGKM0();                                                                      \
    if ((T) + 2 < NT) { VMCNT(4); } else { VMCNT(0); }                            \
} while (0)

#define LOADA(DST, I, LAB) do {                                                   \
    DST[0] = *(const bf16x8*)&LAB[(aro + (I) * 16) * 64 + ch0];                   \
    DST[1] = *(const bf16x8*)&LAB[(aro + (I) * 16) * 64 + ch1];                   \
} while (0)
#define BURST(I, AR) do {                                                         \
    _Pragma("unroll") for (int j = 0; j < 4; ++j) {                               \
        acc[I][j] = __builtin_amdgcn_mfma_f32_16x16x32_bf16(                      \
            AR[0], bf_[j][0], acc[I][j], 0, 0, 0);                                \
        acc[I][j] = __builtin_amdgcn_mfma_f32_16x16x32_bf16(                      \
            AR[1], bf_[j][1], acc[I][j], 0, 0, 0);                                \
    }                                                                             \
} while (0)

// Consumer tile body: read B frags + stream A frags one burst ahead.
#define CONSUME(T) do {                                                           \
    const unsigned short* _la = LA + ((T) & 1) * 16384;                           \
    const unsigned short* _lb = LB + ((T) & 1) * 8192;                            \
    bf16x8 bf_[4][2];                                                             \
    _Pragma("unroll") for (int j = 0; j < 4; ++j) {                               \
        bf_[j][0] = *(const bf16x8*)&_lb[(bro + j * 16) * 64 + ch0];              \
        bf_[j][1] = *(const bf16x8*)&_lb[(bro + j * 16) * 64 + ch1];              \
    }                                                                             \
    bf16x8 aX[2], aY[2];                                                          \
    LOADA(aX, 0, _la);                                                            \
    LOADA(aY, 1, _la); BURST(0, aX);                                              \
    LOADA(aX, 2, _la); BURST(1, aY);                                              \
    LOADA(aY, 3, _la); BURST(2, aX);                                              \
    LOADA(aX, 4, _la); BURST(3, aY);                                              \
    LOADA(aY, 5, _la); BURST(4, aX);                                              \
    LOADA(aX, 6, _la); BURST(5, aY);                                              \
    LOADA(aY, 7, _la); BURST(6, aX);                                              \
    BURST(7, aY);                                                                 \
    LGKM0();                                                                      \
} while (0)

    // ---------------- prologue ----------------
    if (wave >= 4) {
        {   // packed(0)+cb -> set A
            const int4* _pp = (const int4*)Pg;
            pA0 = _pp[0]; pA1 = _pp[1]; pA2 = _pp[2];
            const float4* _cc = (const float4*)Cg;
            cA0 = _cc[0]; cA1 = _cc[1];
        }
        GLD_A(0, 0);                 // A(0) -> LA[0]
        // compiler inserts precise vmcnt(8) before first pA use (forces packed(0))
        DECODE_TILE(0, pA0, pA1, pA2, cA0, cA1);   // B(0) -> LB[0]
        {   // packed(1)+cb -> set B
            const int4* _pp = (const int4*)(Pg + 24);
            pB0 = _pp[0]; pB1 = _pp[1]; pB2 = _pp[2];
            const float4* _cc = (const float4*)Cg;   // block (1>>1)=0
            cB0 = _cc[0]; cB1 = _cc[1];
        }
        LGKM0();
        VMCNT(4);                    // force the 8 gld16; leave packed(1) in flight
    }
    BAR();
    if (wave < 4) __builtin_amdgcn_s_setprio(1);

    // ---------------- main loop: 1 barrier per K-tile ----------------
    for (int t = 0; t < NT; t += 2) {
        if (wave < 4) CONSUME(t);
        else PRODUCE(t, pB0, pB1, pB2, cB0, cB1, pA0, pA1, pA2, cA0, cA1);
        BAR();
        if (wave < 4) CONSUME(t + 1);
        else PRODUCE(t + 1, pA0, pA1, pA2, cA0, cA1, pB0, pB1, pB2, cB0, cB1);
        BAR();
    }

    // ---------------- epilogue (consumers only) ----------------
    if (wave < 4) {
        __builtin_amdgcn_s_setprio(0);
        // C/D layout: col = lane&15, row = (lane>>4)*4 + r  (m89/m91)
#pragma unroll
        for (int i = 0; i < 8; ++i) {
#pragma unroll
            for (int j = 0; j < 4; ++j) {
                int row = bm + qm * 128 + i * 16 + q * 4;
                int col = bn + qn * 64 + j * 16 + r15;
                float* outp = C + (size_t)row * Ndim + col;
#pragma unroll
                for (int r = 0; r < 4; ++r)
                    outp[(size_t)r * Ndim] = acc[i][j][r];
            }
        }
    }

#undef GLD_A
#undef DECG
#undef DECODE_TILE
#undef PRODUCE
#undef LOADA
#undef BURST
#undef CONSUME
}

// ---------------------------------------------------------------------------
extern "C" void kernel_launch(void* const* d_in, const int* in_sizes, int n_in,
                              void* d_out, int out_size, void* d_ws, size_t ws_size,
                              hipStream_t stream) {
    const float* x      = (const float*)d_in[0];   // 2048 x 8192 fp32
    const int*   packed = (const int*)d_in[1];     // 25165824 int32 (one byte each)
    const float* cb     = (const float*)d_in[2];   // 524288 x 8 fp32
    float* out = (float*)d_out;                    // 2048 x 8192 fp32

    unsigned short* Xb = (unsigned short*)d_ws;    // 32 MB bf16 x

    // 1) x fp32 -> bf16
    k_prep<<<16384, 256, 0, stream>>>(x, Xb);
    // 2) fused dequant+GEMM: 512 blocks (2 serial passes/CU), 512 thr, 96KB LDS
    k_gemm<<<dim3(512), 512, 0, stream>>>(Xb, packed, cb, out);
}

// Round 5
// 525.472 us; speedup vs baseline: 1.2905x; 1.2905x over previous
//
#include <hip/hip_runtime.h>
#include <hip/hip_bf16.h>

// Problem constants
#define Mdim 2048
#define Ndim 8192
#define Kdim 8192
#define NT (Kdim / 64)   // 128 K-tiles of BK=64

typedef __bf16 bf16x8 __attribute__((ext_vector_type(8)));
typedef float f32x4 __attribute__((ext_vector_type(4)));
typedef unsigned short ushort4v __attribute__((ext_vector_type(4)));

__device__ __forceinline__ unsigned short f2bf_rne(float f) {
    unsigned u = __float_as_uint(f);
    u += 0x7fffu + ((u >> 16) & 1u);
    return (unsigned short)(u >> 16);
}

// Decode one 8-elem group (24 payload bits) vs bf16-packed codebook pairs
// (P0=e1:e0, P1=e3:e2, P2=e5:e4, P3=e7:e6). Returns 4 u32 = 8 bf16 in
// element order. Bit-logic correctness-proven in R3/R4 (passed absmax).
__device__ __forceinline__ uint4 dec_group(unsigned b, unsigned P0, unsigned P1,
                                           unsigned P2, unsigned P3) {
    uint4 o;
#pragma unroll
    for (int k = 0; k < 4; ++k) {
        unsigned ia = (b >> (6 * k)) & 3u;
        unsigned ib = (b >> (6 * k + 3)) & 3u;
        unsigned sel = ia * 0x0202u + 0x01000100u + ((ib * 0x0202u) << 16);
        unsigned lo = __builtin_amdgcn_perm(P1, P0, sel);   // entries 0..3
        unsigned hi = __builtin_amdgcn_perm(P3, P2, sel);   // entries 4..7
        unsigned mA = (unsigned)((int)(b << (29 - 6 * k)) >> 31);  // bit 6k+2
        unsigned mB = (unsigned)((int)(b << (26 - 6 * k)) >> 31);  // bit 6k+5
        unsigned m = (mA & 0xFFFFu) | (mB & 0xFFFF0000u);
        (&o.x)[k] = (hi & m) | (lo & ~m);
    }
    return o;
}

// ---------------------------------------------------------------------------
// k_prep_x: x fp32 -> bf16, grid-stride (2048 blocks, 8 iters/thread).
// ---------------------------------------------------------------------------
__global__ __launch_bounds__(256) void k_prep_x(const float* __restrict__ x,
                                                unsigned short* __restrict__ xb) {
    for (size_t u = (size_t)blockIdx.x * 256 + threadIdx.x; u < 4194304u;
         u += 524288u) {
        float4 a = ((const float4*)x)[u];
        ushort4v o;
        o[0] = f2bf_rne(a.x); o[1] = f2bf_rne(a.y);
        o[2] = f2bf_rne(a.z); o[3] = f2bf_rne(a.w);
        ((ushort4v*)xb)[u] = o;
    }
}

// ---------------------------------------------------------------------------
// k_prep_w: dequant 3-bit W -> bf16, grid-stride (2048 blocks, 4 iters).
// Per iter: 4 groups (32 elems): 3x int4 packed loads (48B contiguous),
// 2x float4 codebook, perm-decode, 64B contiguous store.
// ---------------------------------------------------------------------------
__global__ __launch_bounds__(256) void k_prep_w(const int* __restrict__ packed,
                                                const float* __restrict__ cb,
                                                unsigned short* __restrict__ W) {
#pragma unroll 2
    for (size_t th = (size_t)blockIdx.x * 256 + threadIdx.x; th < 2097152u;
         th += 524288u) {
        const size_t g0 = th * 4;                          // group base (%4==0)
        const int4* pv = (const int4*)(packed + g0 * 3);   // 12 ints, 16B aligned
        int4 q0 = pv[0], q1 = pv[1], q2 = pv[2];
        const float4* cv = (const float4*)(cb + ((g0 >> 4) << 3));
        float4 c0 = cv[0], c1 = cv[1];
        unsigned cP0 = (unsigned)f2bf_rne(c0.x) | ((unsigned)f2bf_rne(c0.y) << 16);
        unsigned cP1 = (unsigned)f2bf_rne(c0.z) | ((unsigned)f2bf_rne(c0.w) << 16);
        unsigned cP2 = (unsigned)f2bf_rne(c1.x) | ((unsigned)f2bf_rne(c1.y) << 16);
        unsigned cP3 = (unsigned)f2bf_rne(c1.z) | ((unsigned)f2bf_rne(c1.w) << 16);
        unsigned bits0 = (unsigned)q0.x | ((unsigned)q0.y << 8) | ((unsigned)q0.z << 16);
        unsigned bits1 = (unsigned)q0.w | ((unsigned)q1.x << 8) | ((unsigned)q1.y << 16);
        unsigned bits2 = (unsigned)q1.z | ((unsigned)q1.w << 8) | ((unsigned)q2.x << 16);
        unsigned bits3 = (unsigned)q2.y | ((unsigned)q2.z << 8) | ((unsigned)q2.w << 16);
        unsigned short* wp = W + (g0 << 3);                // 64B contiguous
        *(uint4*)(wp)      = dec_group(bits0, cP0, cP1, cP2, cP3);
        *(uint4*)(wp + 8)  = dec_group(bits1, cP0, cP1, cP2, cP3);
        *(uint4*)(wp + 16) = dec_group(bits2, cP0, cP1, cP2, cP3);
        *(uint4*)(wp + 24) = dec_group(bits3, cP0, cP1, cP2, cP3);
    }
}

// ---------------------------------------------------------------------------
// 256x256 GEMM — R2 version VERBATIM (measured 250 us, MfmaUtil 48%).
// One-phase-ahead LDS->reg pipelining, counted vmcnt, 1 barrier/phase.
// ---------------------------------------------------------------------------
__device__ __forceinline__ void gld16(const unsigned short* g, unsigned short* l) {
    __builtin_amdgcn_global_load_lds(
        (const __attribute__((address_space(1))) unsigned int*)g,
        (__attribute__((address_space(3))) unsigned int*)l, 16, 0, 0);
}

#define BAR()    asm volatile("s_barrier" ::: "memory")
#define FENCE()  asm volatile("" ::: "memory")
#define SBAR0()  __builtin_amdgcn_sched_barrier(0)
#define VMCNT(n) asm volatile("s_waitcnt vmcnt(" #n ")" ::: "memory")

__global__ __launch_bounds__(512, 2) void k_gemm(const unsigned short* __restrict__ A,
                                                 const unsigned short* __restrict__ B,
                                                 float* __restrict__ C) {
    __shared__ unsigned short LA[4 * 8192];   // [buf][half][128*64] = 64 KB
    __shared__ unsigned short LB[4 * 8192];   // 64 KB

    const int tid  = threadIdx.x;
    const int lane = tid & 63;
    const int wave = tid >> 6;               // 0..7
    const int qm = wave >> 2;                // 0..1
    const int qn = wave & 3;                 // 0..3

    const int bid = blockIdx.x;
    const int bm = (bid & 7) * 256;          // XCD-resident A panel
    const int bn = (bid >> 3) * 256;

    const int chunk0 = tid, chunk1 = tid + 512;
    const int srow0 = chunk0 >> 3, srow1 = chunk1 >> 3;
    const int scol0 = ((chunk0 & 7) ^ (srow0 & 7)) * 8;
    const int scol1 = ((chunk1 & 7) ^ (srow1 & 7)) * 8;
    const unsigned short* Ag0 = A + (size_t)(bm + srow0) * Kdim + scol0;
    const unsigned short* Ag1 = A + (size_t)(bm + srow1) * Kdim + scol1;
    const unsigned short* Bg0 = B + (size_t)(bn + srow0) * Kdim + scol0;
    const unsigned short* Bg1 = B + (size_t)(bn + srow1) * Kdim + scol1;

#define STAGE_A(T, H, BUF) do {                                                   \
    unsigned short* _d = LA + ((BUF) * 2 + (H)) * 8192;                           \
    gld16(Ag0 + (size_t)(H) * 128 * Kdim + (size_t)(T) * 64, _d + (size_t)tid * 8);        \
    gld16(Ag1 + (size_t)(H) * 128 * Kdim + (size_t)(T) * 64, _d + (size_t)(tid + 512) * 8);\
    FENCE();                                                                      \
} while (0)
#define STAGE_B(T, H, BUF) do {                                                   \
    unsigned short* _d = LB + ((BUF) * 2 + (H)) * 8192;                           \
    gld16(Bg0 + (size_t)(H) * 128 * Kdim + (size_t)(T) * 64, _d + (size_t)tid * 8);        \
    gld16(Bg1 + (size_t)(H) * 128 * Kdim + (size_t)(T) * 64, _d + (size_t)(tid + 512) * 8);\
    FENCE();                                                                      \
} while (0)

    const int r15 = lane & 15;
    const int q   = lane >> 4;
    const int rlo = r15 & 7;
    const int aro = qm * 64 + r15;
    const int bro = qn * 32 + r15;
    const int ch0 = ((0 + q) ^ rlo) * 8;
    const int ch1 = ((4 + q) ^ rlo) * 8;

    f32x4 acc[4][4][2];
    const f32x4 zero = {0.f, 0.f, 0.f, 0.f};
#pragma unroll
    for (int p = 0; p < 4; ++p)
#pragma unroll
        for (int i = 0; i < 4; ++i)
#pragma unroll
            for (int j = 0; j < 2; ++j) acc[p][i][j] = zero;

    bf16x8 aF[4][2];          // single A set: holds lo, then hi (reg reuse)
    bf16x8 bX[2][2][2];       // [half][j][kk] current-parity B
    bf16x8 bY[2][2][2];       // next-parity B

#define LOAD_AF(BUF, H) do {                                                      \
    const unsigned short* _s = LA + ((BUF) * 2 + (H)) * 8192;                     \
    _Pragma("unroll") for (int i = 0; i < 4; ++i) {                               \
        int _r = (aro + i * 16) * 64;                                             \
        aF[i][0] = *(const bf16x8*)&_s[_r + ch0];                                 \
        aF[i][1] = *(const bf16x8*)&_s[_r + ch1];                                 \
    }                                                                             \
} while (0)
#define LOAD_BALL(BUF, BSET) do {                                                 \
    _Pragma("unroll") for (int _h = 0; _h < 2; ++_h) {                            \
        const unsigned short* _s = LB + ((BUF) * 2 + _h) * 8192;                  \
        _Pragma("unroll") for (int j = 0; j < 2; ++j) {                           \
            int _r = (bro + j * 16) * 64;                                         \
            BSET[_h][j][0] = *(const bf16x8*)&_s[_r + ch0];                       \
            BSET[_h][j][1] = *(const bf16x8*)&_s[_r + ch1];                       \
        }                                                                         \
    }                                                                             \
} while (0)

#define MFMA_PH(P, BSET, H) do {                                                  \
    __builtin_amdgcn_s_setprio(1);                                                \
    _Pragma("unroll") for (int i = 0; i < 4; ++i)                                 \
    _Pragma("unroll") for (int j = 0; j < 2; ++j) {                               \
        acc[P][i][j] = __builtin_amdgcn_mfma_f32_16x16x32_bf16(                   \
            aF[i][0], BSET[(H)][j][0], acc[P][i][j], 0, 0, 0);                    \
        acc[P][i][j] = __builtin_amdgcn_mfma_f32_16x16x32_bf16(                   \
            aF[i][1], BSET[(H)][j][1], acc[P][i][j], 0, 0, 0);                    \
    }                                                                             \
    __builtin_amdgcn_s_setprio(0);                                                \
} while (0)

// Quadrants: P0 = Alo x Blo, P1 = Alo x Bhi, P2 = Ahi x Bhi, P3 = Ahi x Blo.
#define KSTEP(T, BUF, BCUR, BNXT) do {                                            \
    /* P0 */                                                                      \
    if ((T) + 1 < NT) { VMCNT(6); STAGE_A((T) + 1, 1, (BUF) ^ 1); }               \
    else              { VMCNT(0); }                                               \
    MFMA_PH(0, BCUR, 0);                                                          \
    BAR();                                                                        \
    /* P1 */                                                                      \
    if ((T) + 1 < NT) { VMCNT(4); }                                               \
    if ((T) + 2 < NT) STAGE_B((T) + 2, 0, BUF);                                   \
    MFMA_PH(1, BCUR, 1);                                                          \
    SBAR0();                                                                      \
    LOAD_AF(BUF, 1);              /* Ahi(T) into aF (Alo dead after P1) */        \
    BAR();                                                                        \
    /* P2 */                                                                      \
    if ((T) + 1 < NT) {                                                           \
        if ((T) + 2 < NT) { VMCNT(4); } else { VMCNT(2); }                        \
        LOAD_BALL((BUF) ^ 1, BNXT);                                               \
    }                                                                             \
    if ((T) + 2 < NT) STAGE_B((T) + 2, 1, BUF);                                   \
    MFMA_PH(2, BCUR, 1);                                                          \
    BAR();                                                                        \
    /* P3 */                                                                      \
    if ((T) + 2 < NT) STAGE_A((T) + 2, 0, BUF);                                   \
    MFMA_PH(3, BCUR, 0);                                                          \
    SBAR0();                                                                      \
    if ((T) + 1 < NT) LOAD_AF((BUF) ^ 1, 0);   /* Alo(T+1) into aF */             \
    BAR();                                                                        \
} while (0)

    // Prologue: tile0 complete + tile1 {Blo,Bhi,Alo}.
    STAGE_B(0, 0, 0); STAGE_B(0, 1, 0); STAGE_A(0, 0, 0); STAGE_A(0, 1, 0);
    STAGE_B(1, 0, 1); STAGE_B(1, 1, 1); STAGE_A(1, 0, 1);
    asm volatile("s_waitcnt vmcnt(8)" ::: "memory");
    BAR();
    LOAD_BALL(0, bX);      // B(0) both halves
    LOAD_AF(0, 0);         // Alo(0)

    for (int t2 = 0; t2 < NT; t2 += 2) {
        KSTEP(t2, 0, bX, bY);
        KSTEP(t2 + 1, 1, bY, bX);
    }

    // Epilogue. C/D layout: col = lane&15, row = (lane>>4)*4 + r  (m89/m91).
    constexpr int RHs[4] = {0, 0, 1, 1};
    constexpr int CHs[4] = {0, 1, 1, 0};
#pragma unroll
    for (int p = 0; p < 4; ++p) {
#pragma unroll
        for (int i = 0; i < 4; ++i) {
#pragma unroll
            for (int j = 0; j < 2; ++j) {
                int row = bm + RHs[p] * 128 + qm * 64 + i * 16 + q * 4;
                int col = bn + CHs[p] * 128 + qn * 32 + j * 16 + r15;
                float* outp = C + (size_t)row * Ndim + col;
#pragma unroll
                for (int r = 0; r < 4; ++r)
                    outp[(size_t)r * Ndim] = acc[p][i][j][r];
            }
        }
    }

#undef STAGE_A
#undef STAGE_B
#undef LOAD_AF
#undef LOAD_BALL
#undef MFMA_PH
#undef KSTEP
}

// ---------------------------------------------------------------------------
extern "C" void kernel_launch(void* const* d_in, const int* in_sizes, int n_in,
                              void* d_out, int out_size, void* d_ws, size_t ws_size,
                              hipStream_t stream) {
    const float* x      = (const float*)d_in[0];   // 2048 x 8192 fp32
    const int*   packed = (const int*)d_in[1];     // 25165824 int32 (one byte each)
    const float* cb     = (const float*)d_in[2];   // 524288 x 8 fp32
    float* out = (float*)d_out;                    // 2048 x 8192 fp32

    unsigned short* Wb = (unsigned short*)d_ws;                          // 128 MB bf16 W
    unsigned short* Xb = (unsigned short*)d_ws + (size_t)Ndim * Kdim;    // 32 MB bf16 x

    // 1) prep, split for rocprof attribution; grid-stride at 2048 blocks
    k_prep_x<<<2048, 256, 0, stream>>>(x, Xb);
    k_prep_w<<<2048, 256, 0, stream>>>(packed, cb, Wb);
    // 2) GEMM (R2-verbatim): 256 blocks (1/CU), 512 threads, 128 KB LDS
    k_gemm<<<dim3(256), 512, 0, stream>>>(Xb, Wb, out);
}

// Round 6
// 458.138 us; speedup vs baseline: 1.4802x; 1.1470x over previous
//
#include <hip/hip_runtime.h>
#include <hip/hip_bf16.h>

// Problem constants
#define Mdim 2048
#define Ndim 8192
#define Kdim 8192
#define NT (Kdim / 64)   // 128 K-tiles of BK=64

typedef __bf16 bf16x8 __attribute__((ext_vector_type(8)));
typedef float f32x4 __attribute__((ext_vector_type(4)));
typedef unsigned short ushort8 __attribute__((ext_vector_type(8)));
typedef unsigned short ushort4v __attribute__((ext_vector_type(4)));

__device__ __forceinline__ unsigned short f2bf_rne(float f) {
    unsigned u = __float_as_uint(f);
    u += 0x7fffu + ((u >> 16) & 1u);
    return (unsigned short)(u >> 16);
}

__device__ __forceinline__ ushort8 decode8(unsigned bits, float4 c0, float4 c1) {
    ushort8 o;
#pragma unroll
    for (int i = 0; i < 8; ++i) {
        unsigned id = (bits >> (3 * i)) & 7u;
        float a0 = (id & 1) ? c0.y : c0.x;
        float a1 = (id & 1) ? c0.w : c0.z;
        float a2 = (id & 1) ? c1.y : c1.x;
        float a3 = (id & 1) ? c1.w : c1.z;
        float b0 = (id & 2) ? a1 : a0;
        float b1 = (id & 2) ? a3 : a2;
        float v  = (id & 4) ? b1 : b0;
        o[i] = f2bf_rne(v);
    }
    return o;
}

// ---------------------------------------------------------------------------
// Fused prep — R0/R1-proven version VERBATIM (best measured: ~198 us rest).
// Blocks [0,16384): dequant, 2 groups/thread via 3 aligned int2 loads.
// Blocks [16384,32768): x fp32->bf16, one float4 -> ushort4 per thread.
// All streams linear => full DRAM page locality (prep is at its BW floor).
// ---------------------------------------------------------------------------
__global__ __launch_bounds__(256) void k_prep(const int* __restrict__ packed,
                                              const float* __restrict__ cb,
                                              const float* __restrict__ x,
                                              unsigned short* __restrict__ W,
                                              unsigned short* __restrict__ xb) {
    const int t = threadIdx.x;
    if (blockIdx.x < 16384) {
        const size_t th = (size_t)blockIdx.x * 256 + t;    // 0..4194303
        const size_t g0 = th * 2;                          // even group
        const int2* pv = (const int2*)(packed + g0 * 3);   // 6 ints, 8B aligned
        int2 q0 = pv[0], q1 = pv[1], q2 = pv[2];
        unsigned bits0 = (unsigned)(q0.x & 255) | ((unsigned)(q0.y & 255) << 8) |
                         ((unsigned)(q1.x & 255) << 16);
        unsigned bits1 = (unsigned)(q1.y & 255) | ((unsigned)(q2.x & 255) << 8) |
                         ((unsigned)(q2.y & 255) << 16);
        const float4* cv0 = (const float4*)(cb + ((g0 >> 4) << 3));
        const float4* cv1 = (const float4*)(cb + (((g0 + 1) >> 4) << 3));
        float4 c00 = cv0[0], c01 = cv0[1];
        float4 c10 = cv1[0], c11 = cv1[1];
        ushort8 o0 = decode8(bits0, c00, c01);
        ushort8 o1 = decode8(bits1, c10, c11);
        unsigned short* wp = W + (g0 << 3);                // 32B contiguous
        *(ushort8*)(wp)     = o0;
        *(ushort8*)(wp + 8) = o1;
    } else {
        const size_t u = (size_t)(blockIdx.x - 16384) * 256 + t;  // 0..4194303
        float4 a = ((const float4*)x)[u];
        ushort4v o;
        o[0] = f2bf_rne(a.x); o[1] = f2bf_rne(a.y);
        o[2] = f2bf_rne(a.z); o[3] = f2bf_rne(a.w);
        ((ushort4v*)xb)[u] = o;
    }
}

// ---------------------------------------------------------------------------
// 256x256 GEMM — R2 structure (proven 250 us), ONE change: block->tile
// mapping inverted so all 8 readers of a W panel co-reside on ONE XCD.
//   bm = (bid>>5)*256, bn = (bid&31)*256.
// XCD(bid) = bid&7; readers of W panel bn are bids ≡ bn (mod 32), all with
// bid&7 = bn&7 -> same XCD. W panel live K-window (32KB/K-tile x 4 panels)
// stays L2-resident there -> W fetched from HBM ~once (was ~4x = 541 MB).
// A panels (32 MB total) shared across XCDs via L3.
// Everything else byte-identical to R2: one-phase-ahead LDS->reg pipelining,
// counted vmcnt, 1 barrier/phase, XOR-chunk swizzle, 0 bank conflicts.
// ---------------------------------------------------------------------------
__device__ __forceinline__ void gld16(const unsigned short* g, unsigned short* l) {
    __builtin_amdgcn_global_load_lds(
        (const __attribute__((address_space(1))) unsigned int*)g,
        (__attribute__((address_space(3))) unsigned int*)l, 16, 0, 0);
}

#define BAR()    asm volatile("s_barrier" ::: "memory")
#define FENCE()  asm volatile("" ::: "memory")
#define SBAR0()  __builtin_amdgcn_sched_barrier(0)
#define VMCNT(n) asm volatile("s_waitcnt vmcnt(" #n ")" ::: "memory")

__global__ __launch_bounds__(512, 2) void k_gemm(const unsigned short* __restrict__ A,
                                                 const unsigned short* __restrict__ B,
                                                 float* __restrict__ C) {
    __shared__ unsigned short LA[4 * 8192];   // [buf][half][128*64] = 64 KB
    __shared__ unsigned short LB[4 * 8192];   // 64 KB

    const int tid  = threadIdx.x;
    const int lane = tid & 63;
    const int wave = tid >> 6;               // 0..7
    const int qm = wave >> 2;                // 0..1
    const int qn = wave & 3;                 // 0..3

    const int bid = blockIdx.x;
    const int bm = (bid >> 5) * 256;         // 8 A panels
    const int bn = (bid & 31) * 256;         // W panel; XCD = bid&7 = bn&7

    const int chunk0 = tid, chunk1 = tid + 512;
    const int srow0 = chunk0 >> 3, srow1 = chunk1 >> 3;
    const int scol0 = ((chunk0 & 7) ^ (srow0 & 7)) * 8;
    const int scol1 = ((chunk1 & 7) ^ (srow1 & 7)) * 8;
    const unsigned short* Ag0 = A + (size_t)(bm + srow0) * Kdim + scol0;
    const unsigned short* Ag1 = A + (size_t)(bm + srow1) * Kdim + scol1;
    const unsigned short* Bg0 = B + (size_t)(bn + srow0) * Kdim + scol0;
    const unsigned short* Bg1 = B + (size_t)(bn + srow1) * Kdim + scol1;

#define STAGE_A(T, H, BUF) do {                                                   \
    unsigned short* _d = LA + ((BUF) * 2 + (H)) * 8192;                           \
    gld16(Ag0 + (size_t)(H) * 128 * Kdim + (size_t)(T) * 64, _d + (size_t)tid * 8);        \
    gld16(Ag1 + (size_t)(H) * 128 * Kdim + (size_t)(T) * 64, _d + (size_t)(tid + 512) * 8);\
    FENCE();                                                                      \
} while (0)
#define STAGE_B(T, H, BUF) do {                                                   \
    unsigned short* _d = LB + ((BUF) * 2 + (H)) * 8192;                           \
    gld16(Bg0 + (size_t)(H) * 128 * Kdim + (size_t)(T) * 64, _d + (size_t)tid * 8);        \
    gld16(Bg1 + (size_t)(H) * 128 * Kdim + (size_t)(T) * 64, _d + (size_t)(tid + 512) * 8);\
    FENCE();                                                                      \
} while (0)

    const int r15 = lane & 15;
    const int q   = lane >> 4;
    const int rlo = r15 & 7;
    const int aro = qm * 64 + r15;
    const int bro = qn * 32 + r15;
    const int ch0 = ((0 + q) ^ rlo) * 8;
    const int ch1 = ((4 + q) ^ rlo) * 8;

    f32x4 acc[4][4][2];
    const f32x4 zero = {0.f, 0.f, 0.f, 0.f};
#pragma unroll
    for (int p = 0; p < 4; ++p)
#pragma unroll
        for (int i = 0; i < 4; ++i)
#pragma unroll
            for (int j = 0; j < 2; ++j) acc[p][i][j] = zero;

    bf16x8 aF[4][2];          // single A set: holds lo, then hi (reg reuse)
    bf16x8 bX[2][2][2];       // [half][j][kk] current-parity B
    bf16x8 bY[2][2][2];       // next-parity B

#define LOAD_AF(BUF, H) do {                                                      \
    const unsigned short* _s = LA + ((BUF) * 2 + (H)) * 8192;                     \
    _Pragma("unroll") for (int i = 0; i < 4; ++i) {                               \
        int _r = (aro + i * 16) * 64;                                             \
        aF[i][0] = *(const bf16x8*)&_s[_r + ch0];                                 \
        aF[i][1] = *(const bf16x8*)&_s[_r + ch1];                                 \
    }                                                                             \
} while (0)
#define LOAD_BALL(BUF, BSET) do {                                                 \
    _Pragma("unroll") for (int _h = 0; _h < 2; ++_h) {                            \
        const unsigned short* _s = LB + ((BUF) * 2 + _h) * 8192;                  \
        _Pragma("unroll") for (int j = 0; j < 2; ++j) {                           \
            int _r = (bro + j * 16) * 64;                                         \
            BSET[_h][j][0] = *(const bf16x8*)&_s[_r + ch0];                       \
            BSET[_h][j][1] = *(const bf16x8*)&_s[_r + ch1];                       \
        }                                                                         \
    }                                                                             \
} while (0)

#define MFMA_PH(P, BSET, H) do {                                                  \
    __builtin_amdgcn_s_setprio(1);                                                \
    _Pragma("unroll") for (int i = 0; i < 4; ++i)                                 \
    _Pragma("unroll") for (int j = 0; j < 2; ++j) {                               \
        acc[P][i][j] = __builtin_amdgcn_mfma_f32_16x16x32_bf16(                   \
            aF[i][0], BSET[(H)][j][0], acc[P][i][j], 0, 0, 0);                    \
        acc[P][i][j] = __builtin_amdgcn_mfma_f32_16x16x32_bf16(                   \
            aF[i][1], BSET[(H)][j][1], acc[P][i][j], 0, 0, 0);                    \
    }                                                                             \
    __builtin_amdgcn_s_setprio(0);                                                \
} while (0)

// Quadrants: P0 = Alo x Blo, P1 = Alo x Bhi, P2 = Ahi x Bhi, P3 = Ahi x Blo.
#define KSTEP(T, BUF, BCUR, BNXT) do {                                            \
    /* P0 */                                                                      \
    if ((T) + 1 < NT) { VMCNT(6); STAGE_A((T) + 1, 1, (BUF) ^ 1); }               \
    else              { VMCNT(0); }                                               \
    MFMA_PH(0, BCUR, 0);                                                          \
    BAR();                                                                        \
    /* P1 */                                                                      \
    if ((T) + 1 < NT) { VMCNT(4); }                                               \
    if ((T) + 2 < NT) STAGE_B((T) + 2, 0, BUF);                                   \
    MFMA_PH(1, BCUR, 1);                                                          \
    SBAR0();                                                                      \
    LOAD_AF(BUF, 1);              /* Ahi(T) into aF (Alo dead after P1) */        \
    BAR();                                                                        \
    /* P2 */                                                                      \
    if ((T) + 1 < NT) {                                                           \
        if ((T) + 2 < NT) { VMCNT(4); } else { VMCNT(2); }                        \
        LOAD_BALL((BUF) ^ 1, BNXT);                                               \
    }                                                                             \
    if ((T) + 2 < NT) STAGE_B((T) + 2, 1, BUF);                                   \
    MFMA_PH(2, BCUR, 1);                                                          \
    BAR();                                                                        \
    /* P3 */                                                                      \
    if ((T) + 2 < NT) STAGE_A((T) + 2, 0, BUF);                                   \
    MFMA_PH(3, BCUR, 0);                                                          \
    SBAR0();                                                                      \
    if ((T) + 1 < NT) LOAD_AF((BUF) ^ 1, 0);   /* Alo(T+1) into aF */             \
    BAR();                                                                        \
} while (0)

    // Prologue: tile0 complete + tile1 {Blo,Bhi,Alo}.
    STAGE_B(0, 0, 0); STAGE_B(0, 1, 0); STAGE_A(0, 0, 0); STAGE_A(0, 1, 0);
    STAGE_B(1, 0, 1); STAGE_B(1, 1, 1); STAGE_A(1, 0, 1);
    asm volatile("s_waitcnt vmcnt(8)" ::: "memory");
    BAR();
    LOAD_BALL(0, bX);      // B(0) both halves
    LOAD_AF(0, 0);         // Alo(0)

    for (int t2 = 0; t2 < NT; t2 += 2) {
        KSTEP(t2, 0, bX, bY);
        KSTEP(t2 + 1, 1, bY, bX);
    }

    // Epilogue. C/D layout: col = lane&15, row = (lane>>4)*4 + r  (m89/m91).
    constexpr int RHs[4] = {0, 0, 1, 1};
    constexpr int CHs[4] = {0, 1, 1, 0};
#pragma unroll
    for (int p = 0; p < 4; ++p) {
#pragma unroll
        for (int i = 0; i < 4; ++i) {
#pragma unroll
            for (int j = 0; j < 2; ++j) {
                int row = bm + RHs[p] * 128 + qm * 64 + i * 16 + q * 4;
                int col = bn + CHs[p] * 128 + qn * 32 + j * 16 + r15;
                float* outp = C + (size_t)row * Ndim + col;
#pragma unroll
                for (int r = 0; r < 4; ++r)
                    outp[(size_t)r * Ndim] = acc[p][i][j][r];
            }
        }
    }

#undef STAGE_A
#undef STAGE_B
#undef LOAD_AF
#undef LOAD_BALL
#undef MFMA_PH
#undef KSTEP
}

// ---------------------------------------------------------------------------
extern "C" void kernel_launch(void* const* d_in, const int* in_sizes, int n_in,
                              void* d_out, int out_size, void* d_ws, size_t ws_size,
                              hipStream_t stream) {
    const float* x      = (const float*)d_in[0];   // 2048 x 8192 fp32
    const int*   packed = (const int*)d_in[1];     // 25165824 int32 (one byte each)
    const float* cb     = (const float*)d_in[2];   // 524288 x 8 fp32
    float* out = (float*)d_out;                    // 2048 x 8192 fp32

    unsigned short* Wb = (unsigned short*)d_ws;                          // 128 MB bf16 W
    unsigned short* Xb = (unsigned short*)d_ws + (size_t)Ndim * Kdim;    // 32 MB bf16 x

    // 1) fused prep (R0/R1-proven): dequant + x convert
    k_prep<<<32768, 256, 0, stream>>>(packed, cb, x, Wb, Xb);
    // 2) GEMM: 256 blocks (1/CU), 512 threads, 128 KB LDS, W-panel-per-XCD map
    k_gemm<<<dim3(256), 512, 0, stream>>>(Xb, Wb, out);
}